// Round 2
// 1052.785 us; speedup vs baseline: 1.0352x; 1.0352x over previous
//
#include <hip/hip_runtime.h>
#include <math.h>
#include <float.h>

#define HW    50176   // 224*224
#define HW4   12544   // HW/4
#define B     128
#define C     33
#define NG    100     // groups (fc1 out)
#define NO    10      // outputs (fc2 out)
#define NTOP  20      // max k in TOPKS

// clang native vector type: __builtin_nontemporal_load requires a real
// vector-of-float pointer (HIP's float4 is a struct and is rejected).
typedef float fvec4 __attribute__((ext_vector_type(4)));

// ---------------- Kernel 1: global mean over each (b,c) plane ----------------
// grid = 4224 blocks (one per plane), block = 256 threads.
// 50176 floats = 12544 float4 = 49 float4 per thread, exact (49 = 7x7).
//   * fully unrolled 49-load body: all loads independent & visible to the
//     scheduler -> deep memory-level parallelism instead of 7-deep batches
//   * __launch_bounds__(256, 4): cap VGPR at 128 -> >=4 blocks/CU resident
//     (>=16 waves/CU), guaranteeing enough reads in flight to cover loaded
//     HBM latency (Little's law: need ~40-80KB/CU in flight at queue-loaded
//     latency; this gives >=112KB even at 7 outstanding/wave)
//   * nontemporal loads: 848MB single-pass stream, no reuse -> skip L2/MALL
//     allocation (avoids churn against the preceding 3.39GB fill writeback)
__global__ __launch_bounds__(256, 4) void mean_kernel(const float* __restrict__ maps,
                                                      float* __restrict__ x_sun /* d_out[0..4224) */) {
    const int plane = blockIdx.x;
    const fvec4* p = reinterpret_cast<const fvec4*>(maps + (size_t)plane * HW);
    const int t = threadIdx.x;

    fvec4 acc[7];
    #pragma unroll
    for (int u = 0; u < 7; ++u) acc[u] = (fvec4)(0.f);

    #pragma unroll
    for (int j = 0; j < 7; ++j) {                 // fully unrolled: 49 independent loads
        #pragma unroll
        for (int u = 0; u < 7; ++u) {
            fvec4 v = __builtin_nontemporal_load(&p[t + 256 * (7 * j + u)]);
            acc[u] += v;
        }
    }
    #pragma unroll
    for (int u = 1; u < 7; ++u) acc[0] += acc[u];
    float s = (acc[0].x + acc[0].y) + (acc[0].z + acc[0].w);

    // wave-64 shuffle reduction
    #pragma unroll
    for (int off = 32; off > 0; off >>= 1)
        s += __shfl_down(s, off, 64);

    __shared__ float ws[4];
    const int lane = t & 63, wave = t >> 6;
    if (lane == 0) ws[wave] = s;
    __syncthreads();
    if (t == 0) {
        float tot = (ws[0] + ws[1]) + (ws[2] + ws[3]);
        x_sun[plane] = tot * (1.0f / (float)HW);
    }
}

// ---------------- Kernel 2: tanh -> fc1+relu -> vote top-k sums + dense ------
// grid = 128 blocks (one per batch), block = 128 threads.
// Output layout (floats): [0,4224)  x_sun  [B,C]
//                         [4224, 4224+9*128*10)  x_son stacked [9,B,10]
__global__ __launch_bounds__(128) void head_kernel(const float* __restrict__ x_sun,
                                                   const float* __restrict__ w1,  // [100,33]
                                                   const float* __restrict__ w2,  // [10,100]
                                                   float* __restrict__ out) {
    const int b = blockIdx.x;
    const int t = threadIdx.x;

    __shared__ float th[C];    // tanh(x_sun[b,:])
    __shared__ float g[NG];    // x_groups[b,:]

    if (t < C) th[t] = tanhf(x_sun[b * C + t]);
    __syncthreads();

    if (t < NG) {
        float s = 0.f;
        #pragma unroll
        for (int c = 0; c < C; ++c) s += th[c] * w1[t * C + c];
        g[t] = s > 0.f ? s : 0.f;
    }
    __syncthreads();

    if (t < NO) {
        const int o = t;
        float top[NTOP];
        #pragma unroll
        for (int j = 0; j < NTOP; ++j) top[j] = -FLT_MAX;
        float total = 0.f;

        for (int i = 0; i < NG; ++i) {
            float v = g[i] * w2[o * NG + i];
            total += v;
            if (v > top[NTOP - 1]) {
                // insertion into descending-sorted top[]
                int j = NTOP - 1;
                while (j > 0 && top[j - 1] < v) { top[j] = top[j - 1]; --j; }
                top[j] = v;
            }
        }

        // prefix sums at positions k-1 for k in {3,4,5,6,7,10,15,20}
        const int kpos[8] = {2, 3, 4, 5, 6, 9, 14, 19};
        float csum = 0.f;
        float res[8];
        int ki = 0;
        #pragma unroll
        for (int j = 0; j < NTOP; ++j) {
            csum += top[j];
            if (ki < 8 && j == kpos[ki]) { res[ki] = csum; ++ki; }
        }

        float* son = out + B * C;             // [9, B, 10]
        #pragma unroll
        for (int j = 0; j < 8; ++j)
            son[(j * B + b) * NO + o] = res[j];
        son[(8 * B + b) * NO + o] = total;    // dense x_groups @ w2.T
    }
}

extern "C" void kernel_launch(void* const* d_in, const int* in_sizes, int n_in,
                              void* d_out, int out_size, void* d_ws, size_t ws_size,
                              hipStream_t stream) {
    const float* maps = (const float*)d_in[0];
    const float* w1   = (const float*)d_in[1];
    const float* w2   = (const float*)d_in[2];
    float* out = (float*)d_out;

    mean_kernel<<<B * C, 256, 0, stream>>>(maps, out);
    head_kernel<<<B, 128, 0, stream>>>(out, w1, w2, out);
}